// Round 7
// baseline (10013.866 us; speedup 1.0000x reference)
//
#include <hip/hip_runtime.h>

typedef _Float16 f16;
typedef _Float16 f16x8 __attribute__((ext_vector_type(8)));
typedef float f32x4 __attribute__((ext_vector_type(4)));

#define B_ 64
#define S_ 1024
#define E_ 256
#define H_ 512
#define NG 1536
#define V_ 50257

__device__ __forceinline__ float sigm(float x) { return 1.f / (1.f + __expf(-x)); }

#define ALOAD(p) __hip_atomic_load((p), __ATOMIC_RELAXED, __HIP_MEMORY_SCOPE_AGENT)
#define ASTORE(p, v) __hip_atomic_store((p), (v), __ATOMIC_RELAXED, __HIP_MEMORY_SCOPE_AGENT)

// ------------- pack [gate_w slice ; gi_or_gh_w] into fp16 [1536][KK] -------------
__global__ __launch_bounds__(256) void k_packW(const float* __restrict__ gw, int ld, int off,
        const float* __restrict__ g2, f16* __restrict__ W, int KK) {
    int idx = blockIdx.x * 256 + threadIdx.x;
    int per = KK >> 2;
    if (idx >= NG * per) return;
    int row = idx / per;
    int c4 = (idx % per) << 2;
    const float* src = (row < 1024) ? gw + (size_t)row * ld + off + c4
                                    : g2 + (size_t)(row - 1024) * KK + c4;
    float4 v = *reinterpret_cast<const float4*>(src);
    union { f16 h[4]; unsigned long long u; } w;
    w.h[0] = (f16)v.x; w.h[1] = (f16)v.y; w.h[2] = (f16)v.z; w.h[3] = (f16)v.w;
    *reinterpret_cast<unsigned long long*>(W + (size_t)row * KK + c4) = w.u;
}

// ------------------------- emb fp32 -> fp16 (one-time) -------------------------
__global__ __launch_bounds__(256) void k_embconv(const float* __restrict__ emb,
        f16* __restrict__ out) {
    long long i = (long long)blockIdx.x * 256 + threadIdx.x;      // float4 quads
    if (i >= (long long)V_ * E_ / 4) return;
    float4 v = reinterpret_cast<const float4*>(emb)[i];
    union { f16 h[4]; unsigned long long u; } w;
    w.h[0] = (f16)v.x; w.h[1] = (f16)v.y; w.h[2] = (f16)v.z; w.h[3] = (f16)v.w;
    reinterpret_cast<unsigned long long*>(out)[i] = w.u;
}

// ------------------------ fused persistent 2-layer GRU, merged layers ------------------------
// 256 WGs x 256 thr (1/CU). c = blk&7 (cluster of 8 batches, XCD-local), gg = blk>>3
// (0..31): WG owns outputs [gg*16,+16) of BOTH layers. Wave w: 4 outputs/layer = 1 MFMA
// tile/layer; A-rows {r,z,n_h,n_x} so h- and x-matmuls accumulate into one C tile.
// Per step: phase A (L0, poll-free) -> publish h0(s+1) -> ONE poll -> ONE dual stage
// (h0(s+1) serves L1-x now AND next step's L0-h) -> phase B (L1) -> publish h1(s+1).
// Only ONE exposed cross-WG hop per step (flag0). LDS fragment layout
// [k>>5][(k>>3)&3][b][k&7] gives all-distinct bank quads -> zero MFMA-read conflicts.
__global__ __launch_bounds__(256, 1) void k_fused(
    const f16* __restrict__ Wx0p, const f16* __restrict__ Wh0p,
    const f16* __restrict__ Wx1p, const f16* __restrict__ Wh1p,
    const float* __restrict__ gb0, const float* __restrict__ gib0, const float* __restrict__ ghb0,
    const float* __restrict__ gb1, const float* __restrict__ gib1, const float* __restrict__ ghb1,
    const int* __restrict__ tok, const f16* __restrict__ embh,
    f16* h0buf, f16* h1buf, int* flags)
{
    __shared__ __align__(16) f16 HS0[4096];        // h0 staged (8 batches x 512)
    __shared__ __align__(16) f16 HS1[4096];        // h1 staged
    __shared__ __align__(16) f16 XLS[2][2048];     // x(t) double buffer (8 x 256)
    __shared__ __align__(16) f16 hx0[8][20];
    __shared__ __align__(16) f16 hx1[8][20];
    const int blk = blockIdx.x;
    const int c = blk & 7;
    const int gg = blk >> 3;                       // 0..31
    const int tid = threadIdx.x;
    const int w = tid >> 6, lane = tid & 63;
    const int colb = lane & 15, bq = lane & 7, j4 = lane >> 4;
    const int aout = (lane & 15) >> 2, aslot = lane & 3;
    const int outA = (gg << 4) + (w << 2) + aout;  // A-fragment row's output
    const int oG   = (gg << 4) + (w << 2) + j4;    // this lane's gate output
    int* flag0 = flags + (c << 6);
    int* flag1 = flag0 + 32;
    unsigned long long* h0q = reinterpret_cast<unsigned long long*>(h0buf); // [4][64][128]
    unsigned long long* h1q = reinterpret_cast<unsigned long long*>(h1buf); // [4][64][128]

    // ---- weights for BOTH layers into registers/AGPRs (constant all steps) ----
    f16x8 wh0[16], wx0[8], wh1[16], wx1[16];
    {
        const int rH = (aslot < 3) ? (aslot * 512 + outA) : -1;
        const int rX = (aslot < 2) ? (aslot * 512 + outA) : (aslot == 3 ? 1024 + outA : -1);
        #pragma unroll
        for (int t = 0; t < 16; ++t) {
            f16x8 v{};
            if (rH >= 0) v = *(const f16x8*)(Wh0p + (size_t)rH * 512 + (t << 5) + (j4 << 3));
            wh0[t] = v;
        }
        #pragma unroll
        for (int t = 0; t < 8; ++t) {
            f16x8 v{};
            if (rX >= 0) v = *(const f16x8*)(Wx0p + (size_t)rX * 256 + (t << 5) + (j4 << 3));
            wx0[t] = v;
        }
        #pragma unroll
        for (int t = 0; t < 16; ++t) {
            f16x8 v{};
            if (rH >= 0) v = *(const f16x8*)(Wh1p + (size_t)rH * 512 + (t << 5) + (j4 << 3));
            wh1[t] = v;
        }
        #pragma unroll
        for (int t = 0; t < 16; ++t) {
            f16x8 v{};
            if (rX >= 0) v = *(const f16x8*)(Wx1p + (size_t)rX * 512 + (t << 5) + (j4 << 3));
            wx1[t] = v;
        }
    }
    const float bR0 = gb0[oG], bZ0 = gb0[512 + oG], bI0 = gib0[oG], bH0 = ghb0[oG];
    const float bR1 = gb1[oG], bZ1 = gb1[512 + oG], bI1 = gib1[oG], bH1 = ghb1[oG];

    // ---- prologue: HS0 = h0(0) = 0 ; XLS[0] = x(0) ----
    {
        unsigned long long* z0 = reinterpret_cast<unsigned long long*>(HS0);
        #pragma unroll
        for (int i = 0; i < 4; ++i) z0[tid + (i << 8)] = 0ULL;
        if (tid < 128) {
            int sb = tid >> 4, seg = tid & 15;
            int tk = tok[((c << 3) + sb) * S_];
            const f16* ep = embh + (size_t)tk * E_ + (seg << 4);
            *(f16x8*)&XLS[0][(seg << 7) + (sb << 3)]      = *(const f16x8*)ep;
            *(f16x8*)&XLS[0][(seg << 7) + 64 + (sb << 3)] = *(const f16x8*)(ep + 8);
        }
        __syncthreads();
    }

    int cur = 0;
    for (int s = 0; s < S_; ++s) {
        // ---- (1) x(s+1) gather into regs (hides under phase A) ----
        f16x8 e0{}, e1{};
        const bool havex = (tid < 128) && (s + 1 < S_);
        if (havex) {
            int tk = tok[((c << 3) + (tid >> 4)) * S_ + s + 1];
            const f16* ep = embh + (size_t)tk * E_ + ((tid & 15) << 4);
            e0 = *(const f16x8*)ep; e1 = *(const f16x8*)(ep + 8);
        }
        // ---- (2) phase A: L0 MFMA (poll-free; HS0 = h0(s), XLS[cur] = x(s)) ----
        {
            f32x4 a0{}, a1{};
            #pragma unroll
            for (int t = 0; t < 16; ++t) {
                f16x8 bf = *(const f16x8*)&HS0[(t << 8) + (j4 << 6) + (bq << 3)];
                if (t & 1) a1 = __builtin_amdgcn_mfma_f32_16x16x32_f16(wh0[t], bf, a1, 0, 0, 0);
                else       a0 = __builtin_amdgcn_mfma_f32_16x16x32_f16(wh0[t], bf, a0, 0, 0, 0);
            }
            #pragma unroll
            for (int t = 0; t < 8; ++t) {
                f16x8 bf = *(const f16x8*)&XLS[cur][(t << 8) + (j4 << 6) + (bq << 3)];
                if (t & 1) a1 = __builtin_amdgcn_mfma_f32_16x16x32_f16(wx0[t], bf, a1, 0, 0, 0);
                else       a0 = __builtin_amdgcn_mfma_f32_16x16x32_f16(wx0[t], bf, a0, 0, 0, 0);
            }
            f32x4 d = a0 + a1;                     // {r, z, n_h, n_x}
            if (colb < 8) {
                float r = sigm(d[0] + bR0), z = sigm(d[1] + bZ0);
                float n = tanhf(d[3] + bI0 + r * (d[2] + bH0));
                float hold = (float)HS0[((oG >> 5) << 8) + (((oG >> 3) & 3) << 6) + (colb << 3) + (oG & 7)];
                hx0[colb][(w << 2) + j4] = (f16)((1.f - z) * n + z * hold);
            }
        }
        __syncthreads();
        // ---- (3) publish h0(s+1) + x->LDS + drain + flag0 ----
        if (tid < 32) {
            int b = tid >> 2, q = tid & 3;
            unsigned long long v = *(unsigned long long*)&hx0[b][q << 2];
            ASTORE(h0q + ((size_t)((s + 1) & 3) * 64 + (c << 3) + b) * 128 + (gg << 2) + q, v);
        }
        if (havex) {
            int sb = tid >> 4, seg = tid & 15;
            *(f16x8*)&XLS[cur ^ 1][(seg << 7) + (sb << 3)]      = e0;
            *(f16x8*)&XLS[cur ^ 1][(seg << 7) + 64 + (sb << 3)] = e1;
        }
        asm volatile("s_waitcnt vmcnt(0)" ::: "memory");
        if (tid == 0) ASTORE(flag0 + gg, s + 1);
        // ---- (4) the ONE poll: h0(s+1) all published; h1(s) all published ----
        {
            const int* fp = (lane < 32) ? (flag0 + lane) : (flag1 + (lane - 32));
            const int tgt = (lane < 32) ? (s + 1) : s;
            while (!__all(ALOAD(fp) >= tgt)) {}
        }
        // ---- (5) dual stage: HS0 <- h0(s+1), HS1 <- h1(s) ----
        {
            const size_t r0 = ((size_t)((s + 1) & 3) * 64 + (c << 3)) * 128;
            const size_t r1 = ((size_t)(s & 3) * 64 + (c << 3)) * 128;
            #pragma unroll
            for (int it = 0; it < 4; ++it) {
                int j = tid + (it << 8);
                int b = j & 7, kq = j >> 3;
                unsigned long long v0 = ALOAD(h0q + r0 + (b << 7) + kq);
                unsigned long long v1 = ALOAD(h1q + r1 + (b << 7) + kq);
                int dst = ((kq >> 3) << 8) + (((kq >> 1) & 3) << 6) + (b << 3) + ((kq & 1) << 2);
                *(unsigned long long*)&HS0[dst] = v0;
                *(unsigned long long*)&HS1[dst] = v1;
            }
        }
        __syncthreads();
        // ---- (6) phase B: L1 MFMA (h = HS1 = h1(s), x = HS0 = h0(s+1)) ----
        {
            f32x4 a0{}, a1{};
            #pragma unroll
            for (int t = 0; t < 16; ++t) {
                f16x8 bf = *(const f16x8*)&HS1[(t << 8) + (j4 << 6) + (bq << 3)];
                if (t & 1) a1 = __builtin_amdgcn_mfma_f32_16x16x32_f16(wh1[t], bf, a1, 0, 0, 0);
                else       a0 = __builtin_amdgcn_mfma_f32_16x16x32_f16(wh1[t], bf, a0, 0, 0, 0);
            }
            #pragma unroll
            for (int t = 0; t < 16; ++t) {
                f16x8 bf = *(const f16x8*)&HS0[(t << 8) + (j4 << 6) + (bq << 3)];
                if (t & 1) a1 = __builtin_amdgcn_mfma_f32_16x16x32_f16(wx1[t], bf, a1, 0, 0, 0);
                else       a0 = __builtin_amdgcn_mfma_f32_16x16x32_f16(wx1[t], bf, a0, 0, 0, 0);
            }
            f32x4 d = a0 + a1;                     // {r, z, n_h, n_x}
            if (colb < 8) {
                float r = sigm(d[0] + bR1), z = sigm(d[1] + bZ1);
                float n = tanhf(d[3] + bI1 + r * (d[2] + bH1));
                float hold = (float)HS1[((oG >> 5) << 8) + (((oG >> 3) & 3) << 6) + (colb << 3) + (oG & 7)];
                hx1[colb][(w << 2) + j4] = (f16)((1.f - z) * n + z * hold);
            }
        }
        __syncthreads();
        // ---- (7) publish h1(s+1) + drain + flag1 (slack: not polled until next (4)) ----
        if (tid < 32) {
            int b = tid >> 2, q = tid & 3;
            unsigned long long v = *(unsigned long long*)&hx1[b][q << 2];
            ASTORE(h1q + ((size_t)((s + 1) & 3) * 64 + (c << 3) + b) * 128 + (gg << 2) + q, v);
        }
        asm volatile("s_waitcnt vmcnt(0)" ::: "memory");
        if (tid == 0) ASTORE(flag1 + gg, s + 1);
        cur ^= 1;
    }
}

// ------------------------------- final head -------------------------------
__global__ __launch_bounds__(64) void k_final(const f16* __restrict__ h,
        const float* __restrict__ fcw, const float* __restrict__ fcb,
        float* __restrict__ out) {
    int b = threadIdx.x;
    float acc = fcb[0];
    for (int k = 0; k < H_; ++k) acc += (float)h[(size_t)b * H_ + k] * fcw[k];
    out[b] = sigm(acc);
}

extern "C" void kernel_launch(void* const* d_in, const int* in_sizes, int n_in,
                              void* d_out, int out_size, void* d_ws, size_t ws_size,
                              hipStream_t stream) {
    (void)in_sizes; (void)n_in; (void)out_size; (void)ws_size;
    const int*   tokens = (const int*)d_in[0];
    const float* emb  = (const float*)d_in[1];
    const float* fc_w = (const float*)d_in[2];
    const float* fc_b = (const float*)d_in[3];
    const float* gw0  = (const float*)d_in[4];
    const float* gb0  = (const float*)d_in[5];
    const float* giw0 = (const float*)d_in[6];
    const float* gib0 = (const float*)d_in[7];
    const float* ghw0 = (const float*)d_in[8];
    const float* ghb0 = (const float*)d_in[9];
    const float* gw1  = (const float*)d_in[10];
    const float* gb1  = (const float*)d_in[11];
    const float* giw1 = (const float*)d_in[12];
    const float* gib1 = (const float*)d_in[13];
    const float* ghw1 = (const float*)d_in[14];
    const float* ghb1 = (const float*)d_in[15];

    char* base = (char*)d_ws;
    size_t off = 0;
    auto carve = [&](size_t bytes) {
        char* p = base + off;
        off = (off + bytes + 255) & ~(size_t)255;
        return p;
    };
    f16*   embh  = (f16*)carve((size_t)V_ * E_ * 2);          // ~25.7 MB
    f16*   Wx0   = (f16*)carve((size_t)NG * 256 * 2);
    f16*   Wh0   = (f16*)carve((size_t)NG * 512 * 2);
    f16*   Wx1   = (f16*)carve((size_t)NG * 512 * 2);
    f16*   Wh1   = (f16*)carve((size_t)NG * 512 * 2);
    f16*   hbuf0 = (f16*)carve((size_t)4 * B_ * H_ * 2);      // 4-slot ring
    f16*   hbuf1 = (f16*)carve((size_t)4 * B_ * H_ * 2);      // 4-slot ring
    int*   flags = (int*)carve((size_t)8 * 64 * 4);

    hipMemsetAsync(hbuf0, 0, (size_t)4 * B_ * H_ * 2, stream);
    hipMemsetAsync(hbuf1, 0, (size_t)4 * B_ * H_ * 2, stream);
    hipMemsetAsync(flags, 0, (size_t)8 * 64 * 4, stream);

    k_embconv<<<(V_ * E_ / 4 + 255) / 256, 256, 0, stream>>>(emb, embh);
    k_packW<<<384, 256, 0, stream>>>(gw0, 768, 0,    giw0, Wx0, 256);
    k_packW<<<768, 256, 0, stream>>>(gw0, 768, 256,  ghw0, Wh0, 512);
    k_packW<<<768, 256, 0, stream>>>(gw1, 1024, 0,   giw1, Wx1, 512);
    k_packW<<<768, 256, 0, stream>>>(gw1, 1024, 512, ghw1, Wh1, 512);

    k_fused<<<256, 256, 0, stream>>>(Wx0, Wh0, Wx1, Wh1,
                                     gb0, gib0, ghb0, gb1, gib1, ghb1,
                                     tokens, embh, hbuf0, hbuf1, flags);
    // h1(1024) lands in ring slot 1024 & 3 == 0
    k_final<<<1, 64, 0, stream>>>(hbuf1, fc_w, fc_b, (float*)d_out);
}

// Round 9
// 3142.990 us; speedup vs baseline: 3.1861x; 3.1861x over previous
//
#include <hip/hip_runtime.h>

typedef _Float16 f16;
typedef _Float16 f16x8 __attribute__((ext_vector_type(8)));
typedef float f32x4 __attribute__((ext_vector_type(4)));
typedef unsigned long long u64;

#define B_ 64
#define S_ 1024
#define E_ 256
#define H_ 512
#define NG 1536         // 3*H packed gate rows (r | z | n)
#define TCH 128         // timesteps per chunk
#define NCHUNK (S_/TCH)
#define ROWS_CH (TCH*B_)   // 8192
#define HS_LD 544       // 1088B rows: quad-bank = 4*bq + j4 -> all 32 lane-groups distinct

__device__ __forceinline__ float sigm(float x) { return 1.f / (1.f + __expf(-x)); }

#define ALOAD(p) __hip_atomic_load((p), __ATOMIC_RELAXED, __HIP_MEMORY_SCOPE_AGENT)
#define ASTORE(p, v) __hip_atomic_store((p), (v), __ATOMIC_RELAXED, __HIP_MEMORY_SCOPE_AGENT)

// ---------------- embedding gather -> fp16, rows ordered (t, b) ----------------
__global__ __launch_bounds__(256) void k_embed(const int* __restrict__ tok,
        const float* __restrict__ emb, f16* __restrict__ X, int t0) {
    int idx = blockIdx.x * 256 + threadIdx.x;     // ROWS_CH * (E_/4) units
    int r = idx >> 6;                             // chunk-local row
    int c4 = (idx & 63) << 2;
    int t = t0 + (r >> 6), b = r & 63;
    int tk = tok[b * S_ + t];
    float4 v = *reinterpret_cast<const float4*>(emb + (size_t)tk * E_ + c4);
    union { f16 h[4]; u64 u; } w;
    w.h[0] = (f16)v.x; w.h[1] = (f16)v.y; w.h[2] = (f16)v.z; w.h[3] = (f16)v.w;
    *reinterpret_cast<u64*>(X + (size_t)r * E_ + c4) = w.u;
}

// ------------- pack [gate_w slice ; gi_or_gh_w] into fp16 [1536][KK] -------------
__global__ __launch_bounds__(256) void k_packW(const float* __restrict__ gw, int ld, int off,
        const float* __restrict__ g2, f16* __restrict__ W, int KK) {
    int idx = blockIdx.x * 256 + threadIdx.x;
    int per = KK >> 2;
    if (idx >= NG * per) return;
    int row = idx / per;
    int c4 = (idx % per) << 2;
    const float* src = (row < 1024) ? gw + (size_t)row * ld + off + c4
                                    : g2 + (size_t)(row - 1024) * KK + c4;
    float4 v = *reinterpret_cast<const float4*>(src);
    union { f16 h[4]; u64 u; } w;
    w.h[0] = (f16)v.x; w.h[1] = (f16)v.y; w.h[2] = (f16)v.z; w.h[3] = (f16)v.w;
    *reinterpret_cast<u64*>(W + (size_t)row * KK + c4) = w.u;
}

__global__ __launch_bounds__(256) void k_packBias(const float* __restrict__ gb,
        const float* __restrict__ gib, float* __restrict__ bias) {
    int i = blockIdx.x * 256 + threadIdx.x;
    if (i < 1024) bias[i] = gb[i];
    else if (i < NG) bias[i] = gib[i - 1024];
}

// --------- GEMM: C[M,1536] = A[M,K] * Bm[1536,K]^T + bias ; fp16 in/out, fp32 acc ---------
__global__ __launch_bounds__(256) void k_gemm(const f16* __restrict__ A,
        const f16* __restrict__ Bm, const float* __restrict__ bias,
        f16* __restrict__ C, int K) {
    __shared__ f16 As[64][40];
    __shared__ f16 Bs[64][40];
    const int tid = threadIdx.x;
    const int m0 = blockIdx.y << 6, n0 = blockIdx.x << 6;
    const int w = tid >> 6, l = tid & 63;
    const int wr = (w >> 1) << 5, wc = (w & 1) << 5;
    const int srow = tid >> 2, sc8 = (tid & 3) << 3;
    const int fr = l & 15, kl = (l >> 4) << 3;
    f32x4 acc[2][2] = {};
    for (int k0 = 0; k0 < K; k0 += 32) {
        *reinterpret_cast<f16x8*>(&As[srow][sc8]) =
            *reinterpret_cast<const f16x8*>(A + (size_t)(m0 + srow) * K + k0 + sc8);
        *reinterpret_cast<f16x8*>(&Bs[srow][sc8]) =
            *reinterpret_cast<const f16x8*>(Bm + (size_t)(n0 + srow) * K + k0 + sc8);
        __syncthreads();
        f16x8 a0 = *reinterpret_cast<const f16x8*>(&As[wr + fr][kl]);
        f16x8 a1 = *reinterpret_cast<const f16x8*>(&As[wr + 16 + fr][kl]);
        f16x8 b0 = *reinterpret_cast<const f16x8*>(&Bs[wc + fr][kl]);
        f16x8 b1 = *reinterpret_cast<const f16x8*>(&Bs[wc + 16 + fr][kl]);
        acc[0][0] = __builtin_amdgcn_mfma_f32_16x16x32_f16(a0, b0, acc[0][0], 0, 0, 0);
        acc[0][1] = __builtin_amdgcn_mfma_f32_16x16x32_f16(a0, b1, acc[0][1], 0, 0, 0);
        acc[1][0] = __builtin_amdgcn_mfma_f32_16x16x32_f16(a1, b0, acc[1][0], 0, 0, 0);
        acc[1][1] = __builtin_amdgcn_mfma_f32_16x16x32_f16(a1, b1, acc[1][1], 0, 0, 0);
        __syncthreads();
    }
    for (int fm = 0; fm < 2; ++fm)
        for (int fn = 0; fn < 2; ++fn) {
            int col = n0 + wc + (fn << 4) + fr;
            float bv = bias[col];
            for (int j = 0; j < 4; ++j) {
                int rowg = m0 + wr + (fm << 4) + ((l >> 4) << 2) + j;
                C[(size_t)rowg * NG + col] = (f16)(acc[fm][fn][j] + bv);
            }
        }
}

// --------------------------- persistent GRU recurrence, MFMA, tag-granule sync ---------------------------
// 256 WGs x 256 thr (1/CU). Decode: c=blk&7 (cluster of 8 batches), l=(blk>>3)&1 (layer),
// gg=blk>>4 (0..15): WG owns 32 outputs. Wave owns 8 outputs = 2 MFMA tiles of 16 rows
// (4 outputs x {r,z,n_h,pad}). A-frags VGPR/AGPR-resident all steps. h exchange via
// TAG-IN-DATA granules: u64 = (tag = step)<<32 | 2xf16, relaxed agent atomics (8B atomic,
// no tearing). No flags, no drains, no RMW: consumer retries granules until tag==s.
// Ring-4 reuse is race-free: publishing tag s+1 requires having staged tag s, which
// requires all peers past step s-1, hence all stale-slot readers (tag s-3, read at step
// s-3) long done. Memset-0 ring == valid {tag 0, h(0)=0} state.
__global__ __launch_bounds__(256, 1) void k_recur4(
        const f16* __restrict__ Wh0p, const f16* __restrict__ Wh1p,
        const f16* __restrict__ Z0, const f16* __restrict__ Z1,
        const float* __restrict__ ghb0, const float* __restrict__ ghb1,
        u64* ring0, u64* ring1, f16* __restrict__ H0out, f16* __restrict__ h1out,
        int t00, int n0, int t01, int n1) {
    __shared__ __align__(16) f16 HS[8][HS_LD];    // staged h(s), plain row-major
    __shared__ __align__(16) f16 hx[8][40];       // gathered h_next (bank-spread)
    const int blk = blockIdx.x;
    const int c = blk & 7;
    const int l = (blk >> 3) & 1;
    const int gg = blk >> 4;                      // 0..15
    const int nsteps = l ? n1 : n0;
    if (nsteps <= 0) return;
    const int t0 = l ? t01 : t00;
    const f16* __restrict__ Wh = l ? Wh1p : Wh0p;
    const f16* __restrict__ Z  = l ? Z1 : Z0;
    const float* __restrict__ ghb = l ? ghb1 : ghb0;
    u64* ring = l ? ring1 : ring0;                // [4 slots][8 clusters][2048 granules]

    const int i0 = gg << 5;                       // WG's first output
    const int tid = threadIdx.x;
    const int w = tid >> 6;                       // wave -> outputs i0+8w..+8w+7
    const int lane = tid & 63;
    const int colb = lane & 15;                   // C/D col (batch slot; 8-15 dup)
    const int bq = lane & 7;                      // real batch within cluster
    const int j4 = lane >> 4;                     // k-octet for A/B frags; out-group for C/D
    const int rrow = lane & 15;
    const int ol = rrow >> 2, gate = rrow & 3;    // A-row decode: row = ol*4 + gate (3=pad)

    // ---- preload recurrent weights into registers (constant all steps) ----
    f16x8 wA[2][16];
    #pragma unroll
    for (int tl = 0; tl < 2; ++tl) {
        const int out = i0 + (w << 3) + (tl << 2) + ol;
        #pragma unroll
        for (int t = 0; t < 16; ++t) {
            f16x8 v{};
            if (gate < 3)
                v = *reinterpret_cast<const f16x8*>(
                        Wh + ((size_t)(gate * H_ + out)) * H_ + (t << 5) + (j4 << 3));
            wA[tl][t] = v;
        }
    }
    const int outA = i0 + (w << 3) + j4;          // tile 0 gate-math output
    const int outB = outA + 4;                    // tile 1
    const float gbA = ghb[outA], gbB = ghb[outB];

    for (int sl = 0; sl < nsteps; ++sl) {
        const int s = t0 + sl;
        // ---- Z prefetch (independent of h; hides under stage retry) ----
        const size_t zrow = ((size_t)sl * 64 + (c << 3) + bq) * NG;
        float zrA = (float)Z[zrow + outA];
        float zzA = (float)Z[zrow + H_ + outA];
        float znA = (float)Z[zrow + 2 * H_ + outA];
        float zrB = (float)Z[zrow + outB];
        float zzB = (float)Z[zrow + H_ + outB];
        float znB = (float)Z[zrow + 2 * H_ + outB];
        // ---- stage h(s): 8 tagged granules/thread, retry until tag==s ----
        {
            const u64* src = ring + ((size_t)(s & 3) * 8 + c) * 2048;
            u64 g[8];
            #pragma unroll
            for (int i = 0; i < 8; ++i) g[i] = ALOAD(src + (i << 8) + tid);
            #pragma unroll
            for (int i = 0; i < 8; ++i) {
                while ((unsigned)(g[i] >> 32) != (unsigned)s)
                    g[i] = ALOAD(src + (i << 8) + tid);
                // granule (batch=i, producer gg=tid>>4, dword d=tid&15)
                *reinterpret_cast<unsigned*>(
                    &HS[i][((tid >> 4) << 5) + ((tid & 15) << 1)]) = (unsigned)g[i];
            }
        }
        __syncthreads();
        // ---- MFMA: 2 tiles x K=512 (16 k-steps), B-frag shared across tiles ----
        f32x4 a00{}, a01{}, a10{}, a11{};
        #pragma unroll
        for (int t = 0; t < 16; ++t) {
            f16x8 bf = *reinterpret_cast<const f16x8*>(&HS[bq][(t << 5) + (j4 << 3)]);
            if (t & 1) {
                a01 = __builtin_amdgcn_mfma_f32_16x16x32_f16(wA[0][t], bf, a01, 0, 0, 0);
                a11 = __builtin_amdgcn_mfma_f32_16x16x32_f16(wA[1][t], bf, a11, 0, 0, 0);
            } else {
                a00 = __builtin_amdgcn_mfma_f32_16x16x32_f16(wA[0][t], bf, a00, 0, 0, 0);
                a10 = __builtin_amdgcn_mfma_f32_16x16x32_f16(wA[1][t], bf, a10, 0, 0, 0);
            }
        }
        f32x4 dA = a00 + a01;                     // rows: outA {r, z, n_h, pad}
        f32x4 dB = a10 + a11;                     // rows: outB
        // ---- gate math, in-lane; only cols 0-7 real ----
        if (colb < 8) {
            float holdA = (float)HS[bq][outA];
            float holdB = (float)HS[bq][outB];
            float rA = sigm(zrA + dA[0]);
            float zA = sigm(zzA + dA[1]);
            float nA = tanhf(znA + rA * (dA[2] + gbA));
            float rB = sigm(zrB + dB[0]);
            float zB = sigm(zzB + dB[1]);
            float nB = tanhf(znB + rB * (dB[2] + gbB));
            hx[bq][(w << 3) + j4]     = (f16)((1.f - zA) * nA + zA * holdA);
            hx[bq][(w << 3) + 4 + j4] = (f16)((1.f - zB) * nB + zB * holdB);
        }
        __syncthreads();
        // ---- publish h(s+1) as tagged granules (no drain, no flags) ----
        if (tid < 128) {
            const int b = tid >> 4, d = tid & 15;
            unsigned dval = *reinterpret_cast<const unsigned*>(&hx[b][d << 1]);
            u64 gr = ((u64)(unsigned)(s + 1) << 32) | (u64)dval;
            ASTORE(ring + ((size_t)((s + 1) & 3) * 8 + c) * 2048
                        + ((size_t)b << 8) + (gg << 4) + d, gr);
            if (l == 0)
                *reinterpret_cast<unsigned*>(
                    &H0out[((size_t)sl * 64 + (c << 3) + b) * H_ + i0 + (d << 1)]) = dval;
            else if (s == S_ - 1)
                *reinterpret_cast<unsigned*>(
                    &h1out[((size_t)(c << 3) + b) * H_ + i0 + (d << 1)]) = dval;
        }
        __syncthreads();   // hx reuse guard for next step
    }
}

// ------------------------------- final head -------------------------------
__global__ __launch_bounds__(64) void k_final(const f16* __restrict__ h,
        const float* __restrict__ fcw, const float* __restrict__ fcb,
        float* __restrict__ out) {
    int b = threadIdx.x;
    float acc = fcb[0];
    for (int k = 0; k < H_; ++k) acc += (float)h[(size_t)b * H_ + k] * fcw[k];
    out[b] = sigm(acc);
}

extern "C" void kernel_launch(void* const* d_in, const int* in_sizes, int n_in,
                              void* d_out, int out_size, void* d_ws, size_t ws_size,
                              hipStream_t stream) {
    (void)in_sizes; (void)n_in; (void)out_size; (void)ws_size;
    const int*   tokens = (const int*)d_in[0];
    const float* emb  = (const float*)d_in[1];
    const float* fc_w = (const float*)d_in[2];
    const float* fc_b = (const float*)d_in[3];
    const float* gw0  = (const float*)d_in[4];
    const float* gb0  = (const float*)d_in[5];
    const float* giw0 = (const float*)d_in[6];
    const float* gib0 = (const float*)d_in[7];
    const float* ghw0 = (const float*)d_in[8];
    const float* ghb0 = (const float*)d_in[9];
    const float* gw1  = (const float*)d_in[10];
    const float* gb1  = (const float*)d_in[11];
    const float* giw1 = (const float*)d_in[12];
    const float* gib1 = (const float*)d_in[13];
    const float* ghw1 = (const float*)d_in[14];
    const float* ghb1 = (const float*)d_in[15];

    char* base = (char*)d_ws;
    size_t off = 0;
    auto carve = [&](size_t bytes) {
        char* p = base + off;
        off = (off + bytes + 255) & ~(size_t)255;
        return p;
    };
    f16*   Wx0   = (f16*)carve((size_t)NG * 256 * 2);
    f16*   Wh0   = (f16*)carve((size_t)NG * 512 * 2);
    f16*   Wx1   = (f16*)carve((size_t)NG * 512 * 2);
    f16*   Wh1   = (f16*)carve((size_t)NG * 512 * 2);
    float* bias0 = (float*)carve(NG * 4);
    float* bias1 = (float*)carve(NG * 4);
    u64*   ring0 = (u64*)carve((size_t)4 * 8 * 2048 * 8);     // 512 KB
    u64*   ring1 = (u64*)carve((size_t)4 * 8 * 2048 * 8);     // 512 KB
    f16*   h1out = (f16*)carve((size_t)B_ * H_ * 2);
    f16*   Xc    = (f16*)carve((size_t)ROWS_CH * 256 * 2);
    f16*   Zc0   = (f16*)carve((size_t)ROWS_CH * NG * 2);
    f16*   H0c   = (f16*)carve((size_t)ROWS_CH * 512 * 2);
    f16*   Zc1   = (f16*)carve((size_t)ROWS_CH * NG * 2);

    hipMemsetAsync(ring0, 0, (size_t)4 * 8 * 2048 * 8, stream);
    hipMemsetAsync(ring1, 0, (size_t)4 * 8 * 2048 * 8, stream);

    k_packW<<<384, 256, 0, stream>>>(gw0, 768, 0,    giw0, Wx0, 256);
    k_packW<<<768, 256, 0, stream>>>(gw0, 768, 256,  ghw0, Wh0, 512);
    k_packW<<<768, 256, 0, stream>>>(gw1, 1024, 0,   giw1, Wx1, 512);
    k_packW<<<768, 256, 0, stream>>>(gw1, 1024, 512, ghw1, Wh1, 512);
    k_packBias<<<6, 256, 0, stream>>>(gb0, gib0, bias0);
    k_packBias<<<6, 256, 0, stream>>>(gb1, gib1, bias1);

    dim3 gemmGrid(NG / 64, ROWS_CH / 64);   // (24, 128)
    for (int ch = 0; ch < NCHUNK; ++ch) {
        int t0 = ch * TCH;
        k_embed<<<ROWS_CH * 64 / 256, 256, 0, stream>>>(tokens, emb, Xc, t0);
        k_gemm<<<gemmGrid, 256, 0, stream>>>(Xc, Wx0, bias0, Zc0, 256);
        // L0 of chunk ch runs concurrently with L1 of chunk ch-1
        k_recur4<<<256, 256, 0, stream>>>(Wh0, Wh1, Zc0, Zc1, ghb0, ghb1,
                                          ring0, ring1, H0c, h1out,
                                          t0, TCH, t0 - TCH, ch ? TCH : 0);
        k_gemm<<<gemmGrid, 256, 0, stream>>>(H0c, Wx1, bias1, Zc1, 512);
    }
    // drain: last chunk of layer 1
    k_recur4<<<256, 256, 0, stream>>>(Wh0, Wh1, Zc0, Zc1, ghb0, ghb1,
                                      ring0, ring1, H0c, h1out,
                                      0, 0, (NCHUNK - 1) * TCH, TCH);
    k_final<<<1, 64, 0, stream>>>(h1out, fc_w, fc_b, (float*)d_out);
}